// Round 4
// baseline (797.664 us; speedup 1.0000x reference)
//
#include <hip/hip_runtime.h>
#include <math.h>

#define TOKENS 16384
#define EMBD   4096
#define NEXP   64
#define TOPK   8
#define KSPLIT 16
#define KSLICE (EMBD / KSPLIT)   /* 256 */
#define CHUNK  16

typedef float v16f __attribute__((ext_vector_type(16)));

// ---------------------------------------------------------------------------
// Kernel 1: transpose W[64][4096] -> Wt[4096][64] so that for a fixed k the 64
// expert weights are contiguous (enables wave-uniform s_load in GEMM).
// ---------------------------------------------------------------------------
__global__ void transpose_w(const float* __restrict__ W, float* __restrict__ Wt) {
    int idx = blockIdx.x * blockDim.x + threadIdx.x;  // idx = e*4096 + k, coalesced read
    int e = idx >> 12;
    int k = idx & 4095;
    Wt[k * NEXP + e] = W[idx];
}

// ---------------------------------------------------------------------------
// Kernel 2: partial GEMM. lane = token; each lane accumulates all 64 expert
// logits over a K-slice of 256. W rows are wave-uniform -> scalar loads; the
// inner op is v_fmac_f32 vacc, s_w, v_x (1 SGPR + 1 VGPR operand - legal mix).
//
// REGISTER ALLOCATION (rounds 1-3 lesson): private C arrays never SROA'd;
// compiler spilled them to scratch (r2: WRITE 133MB vs 64MB part) or split
// the unified file and shuttled via v_accvgpr_read/write (r3: VGPR_Count=56,
// VALUBusy 60%, 2x duration). ext_vector_type values are first-class SSA ->
// contiguous VGPR tuples, nothing to SROA. Live set: acc0..3 (64) + f (16)
// + xv (16) + addressing ~ 112 < 128 budget of __launch_bounds__(256,4).
//
// Numerics: identical to passing r2/r3 scheme: chunk-16 fp32 partial ->
// slice fp32 accumulator -> f64 cross-slice reduce in topk. absmax 1.95e-3.
// ---------------------------------------------------------------------------
__global__ __launch_bounds__(256, 4) void gemm_partial(
    const float* __restrict__ x, const float* __restrict__ Wt,
    float* __restrict__ part) {
    const int lane = threadIdx.x & 63;
    const int wave = threadIdx.x >> 6;
    const int tok  = blockIdx.x * 256 + wave * 64 + lane;
    const int ks   = blockIdx.y;
    const int kbase = ks * KSLICE;

    const float4* xq = (const float4*)(x + (size_t)tok * EMBD + kbase);

    v16f acc0, acc1, acc2, acc3;
#pragma unroll
    for (int e = 0; e < 16; ++e) { acc0[e] = 0.f; acc1[e] = 0.f; acc2[e] = 0.f; acc3[e] = 0.f; }

    for (int kc = 0; kc < KSLICE / CHUNK; ++kc) {   // 16 chunks of 16 k-steps
        float4 X0 = xq[0], X1 = xq[1], X2 = xq[2], X3 = xq[3];
        xq += 4;
        v16f xv;
        xv[0] = X0.x;  xv[1] = X0.y;  xv[2] = X0.z;  xv[3] = X0.w;
        xv[4] = X1.x;  xv[5] = X1.y;  xv[6] = X1.z;  xv[7] = X1.w;
        xv[8] = X2.x;  xv[9] = X2.y;  xv[10] = X2.z; xv[11] = X2.w;
        xv[12] = X3.x; xv[13] = X3.y; xv[14] = X3.z; xv[15] = X3.w;

        const float* wbase = Wt + (size_t)(kbase + kc * CHUNK) * NEXP;  // wave-uniform

#define QUARTER(Q, ACC)                                                       \
        {                                                                     \
            v16f f;                                                           \
            _Pragma("unroll")                                                 \
            for (int e = 0; e < 16; ++e) f[e] = 0.f;                          \
            _Pragma("unroll")                                                 \
            for (int j = 0; j < CHUNK; ++j) {                                 \
                const float* wr = wbase + j * NEXP + (Q) * 16;                \
                const float xj = xv[j];                                       \
                _Pragma("unroll")                                             \
                for (int e = 0; e < 16; ++e) f[e] = fmaf(wr[e], xj, f[e]);    \
            }                                                                 \
            ACC += f;                                                         \
        }

        QUARTER(0, acc0)
        QUARTER(1, acc1)
        QUARTER(2, acc2)
        QUARTER(3, acc3)
#undef QUARTER
    }

    float* dst = part + ((size_t)ks * TOKENS + tok) * NEXP;  // 256B-aligned
    ((v16f*)dst)[0] = acc0;
    ((v16f*)dst)[1] = acc1;
    ((v16f*)dst)[2] = acc2;
    ((v16f*)dst)[3] = acc3;
}

// ---------------------------------------------------------------------------
// Kernel 3: reduce K-split partials (fixed order, f64 -> deterministic),
// top-8 via 8 rounds of 64-lane argmax butterfly (tie-break: lower index,
// matching jax.lax.top_k), masked softmax, write probs + indices(as float).
// One wave per token.
// ---------------------------------------------------------------------------
__global__ __launch_bounds__(256) void topk_softmax(
    const float* __restrict__ part, float* __restrict__ probs,
    float* __restrict__ idxout) {
    const int lane = threadIdx.x & 63;   // = expert
    const int wave = threadIdx.x >> 6;
    const int tok  = blockIdx.x * 4 + wave;

    double d = 0.0;
#pragma unroll
    for (int s = 0; s < KSPLIT; ++s)
        d += (double)part[((size_t)s * TOKENS + tok) * NEXP + lane];
    const float logit = (float)d;

    float v = logit;
    float m = 0.0f, denom = 0.0f;
    int myidx = 0;
    unsigned long long selmask = 0ull;

    for (int r = 0; r < TOPK; ++r) {
        float bv = v;
        int   bi = lane;
#pragma unroll
        for (int off = 32; off > 0; off >>= 1) {
            float ov = __shfl_xor(bv, off);
            int   oi = __shfl_xor(bi, off);
            if (ov > bv || (ov == bv && oi < bi)) { bv = ov; bi = oi; }
        }
        if (r == 0) m = bv;              // rounds are descending -> round 0 is max
        denom += expf(bv - m);
        selmask |= 1ull << bi;
        if (lane == r) myidx = bi;       // lane r keeps the rank-r index
        if (lane == bi) v = -INFINITY;   // remove winner for next round
    }

    const float p = ((selmask >> lane) & 1ull) ? (expf(logit - m) / denom) : 0.0f;
    probs[(size_t)tok * NEXP + lane] = p;
    if (lane < TOPK) idxout[(size_t)tok * TOPK + lane] = (float)myidx;
}

// ---------------------------------------------------------------------------
extern "C" void kernel_launch(void* const* d_in, const int* in_sizes, int n_in,
                              void* d_out, int out_size, void* d_ws, size_t ws_size,
                              hipStream_t stream) {
    const float* x = (const float*)d_in[0];   // [4,4096,4096]
    const float* W = (const float*)d_in[1];   // [64,4096]

    float* out    = (float*)d_out;
    float* probs  = out;                         // 16384*64 floats
    float* idxout = out + (size_t)TOKENS * NEXP; // 16384*8 floats (indices as float)

    float* Wt   = (float*)d_ws;                  // 4096*64 floats = 1 MB
    float* part = Wt + (size_t)EMBD * NEXP;      // 16*16384*64 floats = 64 MB

    hipLaunchKernelGGL(transpose_w, dim3((EMBD * NEXP) / 256), dim3(256), 0, stream,
                       W, Wt);
    hipLaunchKernelGGL(gemm_partial, dim3(TOKENS / 256, KSPLIT), dim3(256), 0, stream,
                       x, Wt, part);
    hipLaunchKernelGGL(topk_softmax, dim3(TOKENS / 4), dim3(256), 0, stream,
                       part, probs, idxout);
}